// Round 7
// baseline (90.468 us; speedup 1.0000x reference)
//
#include <hip/hip_runtime.h>
#include <math.h>

// DisCo (distance correlation) for N=8192, scalar output. 6 kernels.
// KEY STRUCTURE (R7): lane<->row mapping. Each lane owns one row i; the
// column loop is WAVE-UNIFORM -> j-streams load via the scalar path (s_load),
// zero L1 vector traffic for j-data, no cross-lane reduction epilogues
// (each lane's (seg,row) partial is complete -> direct coalesced store).
// Algebra (validated R5, absmax 0.0): A_ij = d_ij - r_i - r_j with
// d=|a_i-a_j|, r_i = avg_i - ga/2; polynomial terms are O(N); only the
// |.|-carrying sums are swept pairwise:
//   pass1: P0a[i]=Sum_j w_j|da|, P0b  (4 VALU/pair)
//   pass2: Q=Sum w d e, P1a=Sum (wr)d, P2=Sum (ws)d, P3=Sum (wr)e,
//          P1b=Sum (ws)e              (8 VALU/pair)
// K1 k_pass1 (32x64): per-(seg,row) partials pa,pb [NSEG][N]
// K2 k_mid   (64):    row sums -> avga/avgb; per-block dbl gA/gB partials
// K3 k_wrs   (32):    ha=ga/2 from gA[64]; wr=w*(avg-ha), ws; 10 moments
// K4 k_pass2 (32x64): per-(seg,row) partials q,p1a,p2,p3,p1b [NSEG][N]
// K5 k_tail  (64):    scalars + per-row T_AB/T_AA/T_BB assembly -> f[3][64]
// K6 k_fin   (1x64):  final reduce + power branch + NaN/clamp
// No atomics, no fences (R4 lesson). All reductions fixed-order.
// VGPR discipline (R6 lesson): pass kernels keep tiny register footprints
// (no doubles, no butterflies) to stay at 8 waves/SIMD.

#define NN 8192
#define BLK 256
#define NSEG 64                 // column segments
#define SEGC (NN / NSEG)        // 128 columns per segment
#define RND (SEGC / 4)          // 32 float4 rounds per segment
#define GRIDR (NN / BLK)        // 32 row-groups
#define MIDB 64                 // k_mid / k_tail blocks (128 threads)
#define WRSB 32                 // k_wrs blocks (256 threads)

// ---------------------------------------------------------------- K1: pass 1
__global__ __launch_bounds__(BLK) void k_pass1(
    const float* __restrict__ a, const float* __restrict__ b,
    const float* __restrict__ w,
    float* __restrict__ pa, float* __restrict__ pb) {
  const int row = blockIdx.x * BLK + threadIdx.x;
  const int seg = blockIdx.y;
  const float aiv = a[row], biv = b[row];
  float sa = 0.f, sb = 0.f;

  const float4* a4 = (const float4*)a + seg * RND;   // uniform -> s_load
  const float4* b4 = (const float4*)b + seg * RND;
  const float4* w4 = (const float4*)w + seg * RND;

  float4 A0 = a4[0], B0 = b4[0], W0 = w4[0];
#pragma unroll 1
  for (int r = 0; r < RND - 1; ++r) {
    const float4 A1 = a4[r + 1], B1 = b4[r + 1], W1 = w4[r + 1];
#define P1E(e)                                          \
    sa = fmaf(fabsf(aiv - A0.e), W0.e, sa);             \
    sb = fmaf(fabsf(biv - B0.e), W0.e, sb);
    P1E(x) P1E(y) P1E(z) P1E(w)
    A0 = A1; B0 = B1; W0 = W1;
  }
  P1E(x) P1E(y) P1E(z) P1E(w)
#undef P1E

  pa[seg * NN + row] = sa;
  pb[seg * NN + row] = sb;
}

// ------------------------------------------- K2: row sums -> avg, gA/gB parts
__global__ __launch_bounds__(128) void k_mid(
    const float* __restrict__ w,
    const float* __restrict__ pa, const float* __restrict__ pb,
    float* __restrict__ avga, float* __restrict__ avgb,
    double* __restrict__ gA, double* __restrict__ gB) {
  const int lane = threadIdx.x & 63;
  const int wv = threadIdx.x >> 6;
  const int row = blockIdx.x * 128 + threadIdx.x;

  double ra = 0.0, rb = 0.0;
#pragma unroll 1
  for (int s = 0; s < NSEG; ++s) {
    ra += (double)pa[s * NN + row];
    rb += (double)pb[s * NN + row];
  }
  avga[row] = (float)(ra * (1.0 / NN));
  avgb[row] = (float)(rb * (1.0 / NN));

  const double wi = (double)w[row];
  double da = wi * ra, db = wi * rb;
#pragma unroll
  for (int off = 32; off >= 1; off >>= 1) {
    da += __shfl_xor(da, off);
    db += __shfl_xor(db, off);
  }
  __shared__ double l[2][2];
  if (lane == 0) { l[0][wv] = da; l[1][wv] = db; }
  __syncthreads();
  if (threadIdx.x == 0) {
    gA[blockIdx.x] = l[0][0] + l[0][1];
    gB[blockIdx.x] = l[1][0] + l[1][1];
  }
}

// ------------------------------- K3: ha/hb; wr/ws arrays; 10 moment partials
__global__ __launch_bounds__(BLK) void k_wrs(
    const float* __restrict__ a, const float* __restrict__ b,
    const float* __restrict__ w,
    const float* __restrict__ avga, const float* __restrict__ avgb,
    const double* __restrict__ gA, const double* __restrict__ gB,
    float* __restrict__ wr, float* __restrict__ ws,
    double* __restrict__ scal) {
  const int lane = threadIdx.x & 63;
  const int wv = threadIdx.x >> 6;

  double da = gA[lane], db = gB[lane];   // exactly 64 entries
#pragma unroll
  for (int off = 32; off >= 1; off >>= 1) {
    da += __shfl_xor(da, off);
    db += __shfl_xor(db, off);
  }
  const double n2 = (double)NN * (double)NN;
  const float ha = (float)(0.5 * da / n2);   // ga/2
  const float hb = (float)(0.5 * db / n2);

  const int i = blockIdx.x * BLK + threadIdx.x;
  const float wi = w[i], av = avga[i], bv = avgb[i], aiv = a[i], biv = b[i];
  const float ri = av - ha, si = bv - hb;
  wr[i] = wi * ri;
  ws[i] = wi * si;

  double p[10];
  p[0] = (double)wi;
  p[1] = (double)wi * aiv;
  p[2] = (double)wi * aiv * aiv;
  p[3] = (double)wi * biv;
  p[4] = (double)wi * biv * biv;
  p[5] = (double)wi * ri;
  p[6] = (double)wi * si;
  p[7] = (double)wi * ri * ri;
  p[8] = (double)wi * si * si;
  p[9] = (double)wi * ri * si;
#pragma unroll
  for (int off = 32; off >= 1; off >>= 1) {
#pragma unroll
    for (int t = 0; t < 10; ++t) p[t] += __shfl_xor(p[t], off);
  }
  __shared__ double lp[10][4];
  if (lane == 0) {
#pragma unroll
    for (int t = 0; t < 10; ++t) lp[t][wv] = p[t];
  }
  __syncthreads();
  if (threadIdx.x == 0) {
#pragma unroll
    for (int t = 0; t < 10; ++t)
      scal[t * WRSB + blockIdx.x] = lp[t][0] + lp[t][1] + lp[t][2] + lp[t][3];
  }
}

// ---------------------------------------------------------------- K4: pass 2
__global__ __launch_bounds__(BLK) void k_pass2(
    const float* __restrict__ a, const float* __restrict__ b,
    const float* __restrict__ w,
    const float* __restrict__ wr, const float* __restrict__ ws,
    float* __restrict__ qA, float* __restrict__ p1aA, float* __restrict__ p2A,
    float* __restrict__ p3A, float* __restrict__ p1bA) {
  const int row = blockIdx.x * BLK + threadIdx.x;
  const int seg = blockIdx.y;
  const float aiv = a[row], biv = b[row];
  float q = 0.f, g1a = 0.f, g2 = 0.f, g3 = 0.f, g1b = 0.f;

  const float4* a4 = (const float4*)a  + seg * RND;   // uniform -> s_load
  const float4* b4 = (const float4*)b  + seg * RND;
  const float4* w4 = (const float4*)w  + seg * RND;
  const float4* r4 = (const float4*)wr + seg * RND;
  const float4* s4 = (const float4*)ws + seg * RND;

  float4 A0 = a4[0], B0 = b4[0], W0 = w4[0], R0 = r4[0], S0 = s4[0];
#pragma unroll 1
  for (int r = 0; r < RND - 1; ++r) {
    const float4 A1 = a4[r + 1], B1 = b4[r + 1], W1 = w4[r + 1],
                 R1 = r4[r + 1], S1 = s4[r + 1];
#define P2E(e)                                          \
    {                                                   \
      const float dd = fabsf(aiv - A0.e);               \
      const float ee = fabsf(biv - B0.e);               \
      g1a = fmaf(R0.e, dd, g1a);                        \
      g2  = fmaf(S0.e, dd, g2);                         \
      g3  = fmaf(R0.e, ee, g3);                         \
      g1b = fmaf(S0.e, ee, g1b);                        \
      q   = fmaf(W0.e * dd, ee, q);                     \
    }
    P2E(x) P2E(y) P2E(z) P2E(w)
    A0 = A1; B0 = B1; W0 = W1; R0 = R1; S0 = S1;
  }
  P2E(x) P2E(y) P2E(z) P2E(w)
#undef P2E

  const int o = seg * NN + row;
  qA[o] = q; p1aA[o] = g1a; p2A[o] = g2; p3A[o] = g3; p1bA[o] = g1b;
}

// ------------------ K5: scalars + per-row T assembly + per-block dbl partials
__global__ __launch_bounds__(128) void k_tail(
    const float* __restrict__ a, const float* __restrict__ b,
    const float* __restrict__ w,
    const float* __restrict__ avga, const float* __restrict__ avgb,
    const float* __restrict__ qA, const float* __restrict__ p1aA,
    const float* __restrict__ p2A, const float* __restrict__ p3A,
    const float* __restrict__ p1bA,
    const double* __restrict__ gA, const double* __restrict__ gB,
    const double* __restrict__ scal,
    double* __restrict__ fAB, double* __restrict__ fAA, double* __restrict__ fBB) {
  const int lane = threadIdx.x & 63;
  const int wv = threadIdx.x >> 6;

  __shared__ double sc[10];
  if (threadIdx.x < 10) {
    double s = 0.0;
    for (int k = 0; k < WRSB; ++k) s += scal[threadIdx.x * WRSB + k];
    sc[threadIdx.x] = s;
  }
  double da = gA[lane], db = gB[lane];
#pragma unroll
  for (int off = 32; off >= 1; off >>= 1) {
    da += __shfl_xor(da, off);
    db += __shfl_xor(db, off);
  }
  const double n2 = (double)NN * (double)NN;
  const float ha = (float)(0.5 * da / n2);
  const float hb = (float)(0.5 * db / n2);
  __syncthreads();
  const double W   = sc[0], Ma1 = sc[1], Ma2 = sc[2], Mb1 = sc[3], Mb2 = sc[4];
  const double Swr = sc[5], Sws = sc[6], Swr2 = sc[7], Sws2 = sc[8], Swrs = sc[9];

  const int i = blockIdx.x * 128 + threadIdx.x;
  double Qi = 0.0, P1A = 0.0, P2v = 0.0, P3v = 0.0, P1B = 0.0;
#pragma unroll 1
  for (int s = 0; s < NSEG; ++s) {
    const int o = s * NN + i;
    Qi  += (double)qA[o];
    P1A += (double)p1aA[o];
    P2v += (double)p2A[o];
    P3v += (double)p3A[o];
    P1B += (double)p1bA[o];
  }
  const double av = (double)avga[i], bv = (double)avgb[i];
  const double ri = (double)(avga[i] - ha);
  const double si = (double)(avgb[i] - hb);
  const double aiv = (double)a[i], biv = (double)b[i], wi = (double)w[i];
  const double P0a = av * (double)NN;     // Sum_j w_j d_ij
  const double P0b = bv * (double)NN;

  const double TAB = Qi - si * P0a - P2v - ri * P0b - P3v
                   + ri * si * W + ri * Sws + si * Swr + Swrs;
  const double TAA = (aiv * aiv * W - 2.0 * aiv * Ma1 + Ma2)
                   - 2.0 * ri * P0a - 2.0 * P1A
                   + ri * ri * W + 2.0 * ri * Swr + Swr2;
  const double TBB = (biv * biv * W - 2.0 * biv * Mb1 + Mb2)
                   - 2.0 * si * P0b - 2.0 * P1B
                   + si * si * W + 2.0 * si * Sws + Sws2;

  double ab = fabs(TAB) * wi;
  double aa = TAA * wi;
  double bb = TBB * wi;
#pragma unroll
  for (int off = 32; off >= 1; off >>= 1) {
    ab += __shfl_xor(ab, off);
    aa += __shfl_xor(aa, off);
    bb += __shfl_xor(bb, off);
  }
  __shared__ double l3[3][2];
  if (lane == 0) { l3[0][wv] = ab; l3[1][wv] = aa; l3[2][wv] = bb; }
  __syncthreads();
  if (threadIdx.x == 0) {
    fAB[blockIdx.x] = l3[0][0] + l3[0][1];
    fAA[blockIdx.x] = l3[1][0] + l3[1][1];
    fBB[blockIdx.x] = l3[2][0] + l3[2][1];
  }
}

// ---------------------------------------------------------------- K6: finalize
__global__ __launch_bounds__(64) void k_fin(
    const double* __restrict__ fAB, const double* __restrict__ fAA,
    const double* __restrict__ fBB, const int* __restrict__ powerPtr,
    float* __restrict__ out) {
  const int lane = threadIdx.x;
  double ab = fAB[lane], aa = fAA[lane], bb = fBB[lane];   // MIDB == 64
#pragma unroll
  for (int off = 32; off >= 1; off >>= 1) {
    ab += __shfl_xor(ab, off);
    aa += __shfl_xor(aa, off);
    bb += __shfl_xor(bb, off);
  }
  if (lane == 0) {
    const double n2 = (double)NN * (double)NN;
    const double num = ab / n2;
    const double mAA = aa / n2;
    const double mBB = bb / n2;
    const double den = fabs(mAA * mBB);
    const int p = powerPtr[0];
    double d;
    if (p == 1) {
      d = num / sqrt(den + 1e-12);
    } else if (p == 2) {
      d = (num * num) / (den + 1e-12);
    } else {
      d = pow(num / sqrt(mAA * mBB) + 1e-12, (double)p);
    }
    if (isnan(d)) d = 0.0;
    if (d < 0.0) d = 0.0;
    out[0] = (float)d;
  }
}

// -------------------------------------------------------------------- launcher
extern "C" void kernel_launch(void* const* d_in, const int* in_sizes, int n_in,
                              void* d_out, int out_size, void* d_ws, size_t ws_size,
                              hipStream_t stream) {
  const float* a = (const float*)d_in[0];
  const float* b = (const float*)d_in[1];
  const float* w = (const float*)d_in[2];
  const int* power = (const int*)d_in[3];
  float* out = (float*)d_out;

  double* dws = (double*)d_ws;           // 8B-aligned base
  double* gA   = dws;                    // [64]
  double* gB   = gA + MIDB;              // [64]
  double* scal = gB + MIDB;              // [10*32]
  double* fAB  = scal + 10 * WRSB;       // [64]
  double* fAA  = fAB + MIDB;             // [64]
  double* fBB  = fAA + MIDB;             // [64]
  float* fp   = (float*)(fBB + MIDB);
  float* pa   = fp;                      // [NSEG*NN]
  float* pb   = pa + NSEG * NN;          // [NSEG*NN]
  float* qA   = pb + NSEG * NN;          // [NSEG*NN]
  float* p1aA = qA + NSEG * NN;          // [NSEG*NN]
  float* p2A  = p1aA + NSEG * NN;        // [NSEG*NN]
  float* p3A  = p2A + NSEG * NN;         // [NSEG*NN]
  float* p1bA = p3A + NSEG * NN;         // [NSEG*NN]
  float* avga = p1bA + NSEG * NN;        // [NN]
  float* avgb = avga + NN;               // [NN]
  float* wrv  = avgb + NN;               // [NN]
  float* wsv  = wrv + NN;                // [NN]

  const dim3 gp(GRIDR, NSEG);            // 32 x 64 = 2048 blocks
  k_pass1<<<gp, BLK, 0, stream>>>(a, b, w, pa, pb);
  k_mid<<<MIDB, 128, 0, stream>>>(w, pa, pb, avga, avgb, gA, gB);
  k_wrs<<<WRSB, BLK, 0, stream>>>(a, b, w, avga, avgb, gA, gB, wrv, wsv, scal);
  k_pass2<<<gp, BLK, 0, stream>>>(a, b, w, wrv, wsv, qA, p1aA, p2A, p3A, p1bA);
  k_tail<<<MIDB, 128, 0, stream>>>(a, b, w, avga, avgb, qA, p1aA, p2A, p3A, p1bA,
                                   gA, gB, scal, fAB, fAA, fBB);
  k_fin<<<1, 64, 0, stream>>>(fAB, fAA, fBB, power, out);
}